// Round 11
// baseline (66.497 us; speedup 1.0000x reference)
//
#include <hip/hip_runtime.h>
#include <hip/hip_bf16.h>

// Problem constants:
//   X: (B=16, D=512, 60, 60) fp32 -> N = 3600
//   codewords: (K=32, D=512) fp32, scale: (K=32,) fp32
//   out E: (B, K, D) fp32
constexpr int BB = 16;
constexpr int DD = 512;
constexpr int NN = 3600;
constexpr int KK = 32;
constexpr int SB = 29;     // 128-n windows per batch
constexpr int WIN = 128;

typedef __attribute__((ext_vector_type(8))) short short8;
typedef __attribute__((ext_vector_type(4))) float f32x4;

__device__ inline unsigned bf16pack(float a, float b) {
    unsigned ia = __float_as_uint(a), ib = __float_as_uint(b);
    ia = (ia + 0x7fffu + ((ia >> 16) & 1u)) >> 16;          // RNE to bf16
    ib = (ib + 0x7fffu + ((ib >> 16) & 1u)) & 0xffff0000u;
    return ia | ib;
}

__device__ inline int swzkey(int row) {      // XOR-swizzle key (elems, mult of 8)
    return ((row ^ (row >> 3)) & 7) << 3;
}

// ---------------------------------------------------------------------------
// K0: Cbf[k][d] = bf16(Cw[k][d]);  sc2[k] = scale[k]*sum_d C[k,d]^2
// ---------------------------------------------------------------------------
__global__ __launch_bounds__(256) void k0_prep(const float* __restrict__ Cw,
                                               const float* __restrict__ scale,
                                               ushort* __restrict__ Cbf,
                                               float* __restrict__ sc2) {
    __shared__ float buf[8][32];
    const int t = threadIdx.x;
    const int k = t & 31;
    const int h = t >> 5;   // 0..7, 64 d's each
    const float4* row = reinterpret_cast<const float4*>(Cw + k * DD + h * 64);
    uint2* crow = reinterpret_cast<uint2*>(Cbf + k * DD + h * 64);
    float s = 0.f;
#pragma unroll
    for (int j = 0; j < 16; ++j) {
        float4 v = row[j];
        crow[j] = make_uint2(bf16pack(v.x, v.y), bf16pack(v.z, v.w));
        s += v.x * v.x + v.y * v.y + v.z * v.z + v.w * v.w;
    }
    buf[h][k] = s;
    __syncthreads();
    if (t < 32) {
        float tot = 0.f;
#pragma unroll
        for (int j = 0; j < 8; ++j) tot += buf[j][t];
        sc2[t] = scale[t] * tot;
    }
}

// ---------------------------------------------------------------------------
// KF: fused GEMM1 + softmax + GEMM2, producer/consumer wave specialization.
// Grid: B*SB = 464 blocks x 512 threads; LDS 144 KB -> 1 block/CU.
// Waves 0-3 stream X[:,window] -> swizzled bf16 tile (8 chunks of 64 d),
// never blocking on compute; per-(chunk,producer) LDS flags signal readiness.
// Waves 4-7 spin per chunk and run GEMM1; then softmax -> As2. One barrier,
// then all 8 waves run GEMM2 from the tile. Out: Ep fp32 partials + asum.
// ---------------------------------------------------------------------------
__global__ __launch_bounds__(512) void kf_fused(const float* __restrict__ X,
                                                const ushort* __restrict__ Cbf,
                                                const float* __restrict__ scale,
                                                const float* __restrict__ sc2,
                                                float* __restrict__ Ep,
                                                float* __restrict__ asum_part) {
    __shared__ ushort tile[DD * WIN];     // 128 KB, XOR-swizzled rows
    __shared__ ushort As2[KK * WIN];      // 8 KB, same swizzle per k-row
    __shared__ float x2part[8][WIN];      // 4 KB
    __shared__ float x2s[WIN];            // 512 B
    __shared__ float asw[4][KK];          // 512 B
    __shared__ int flags[8][4];           // chunk x producer

    const int t = threadIdx.x;
    const int w = t >> 6;     // wave 0..7
    const int l = t & 63;
    const int q = l >> 4;     // 0..3
    const int r = l & 15;     // 0..15
    const int b = blockIdx.x / SB;
    const int sb = blockIdx.x % SB;
    const int n0 = sb * WIN;
    const float* Xb = X + (size_t)b * DD * NN;

    if (t < 32) flags[t >> 2][t & 3] = 0;
    __syncthreads();

    if (w < 4) {
        // ======================= PRODUCERS =======================
        const int p = w;
        const int ng = l & 31;          // n-group of 4
        const int dr = l >> 5;          // 0..1
        const int rbase = p * 16 + dr * 8;
        int nst = n0 + ng * 4;
        if (nst > NN - 4) nst = NN - 4;
        const float* xsrc = Xb + nst;
        float x2loc[4] = {0.f, 0.f, 0.f, 0.f};

        float4 bufA[8], bufB[8];
#pragma unroll
        for (int i = 0; i < 8; ++i)
            bufA[i] = *reinterpret_cast<const float4*>(xsrc + (size_t)(rbase + i) * NN);

#define PROD_CHUNK(CURB, NXTB, C)                                              \
        {                                                                      \
            if ((C) < 7) {                                                     \
                _Pragma("unroll")                                              \
                for (int i = 0; i < 8; ++i)                                    \
                    NXTB[i] = *reinterpret_cast<const float4*>(                \
                        xsrc + (size_t)(((C) + 1) * 64 + rbase + i) * NN);     \
            }                                                                  \
            _Pragma("unroll")                                                  \
            for (int i = 0; i < 8; ++i) {                                      \
                const float4 v = CURB[i];                                      \
                x2loc[0] = fmaf(v.x, v.x, x2loc[0]);                           \
                x2loc[1] = fmaf(v.y, v.y, x2loc[1]);                           \
                x2loc[2] = fmaf(v.z, v.z, x2loc[2]);                           \
                x2loc[3] = fmaf(v.w, v.w, x2loc[3]);                           \
                const int d = (C) * 64 + rbase + i;                            \
                *reinterpret_cast<uint2*>(                                     \
                    &tile[d * WIN + ((ng * 4) ^ swzkey(d))]) =                 \
                    make_uint2(bf16pack(v.x, v.y), bf16pack(v.z, v.w));        \
            }                                                                  \
            if ((C) == 7)                                                      \
                *reinterpret_cast<f32x4*>(&x2part[p * 2 + dr][ng * 4]) =       \
                    (f32x4){x2loc[0], x2loc[1], x2loc[2], x2loc[3]};           \
            asm volatile("s_waitcnt lgkmcnt(0)" ::: "memory");                 \
            if (l == 0) *(volatile int*)&flags[(C)][p] = 1;                    \
        }
        PROD_CHUNK(bufA, bufB, 0)
        PROD_CHUNK(bufB, bufA, 1)
        PROD_CHUNK(bufA, bufB, 2)
        PROD_CHUNK(bufB, bufA, 3)
        PROD_CHUNK(bufA, bufB, 4)
        PROD_CHUNK(bufB, bufA, 5)
        PROD_CHUNK(bufA, bufB, 6)
        PROD_CHUNK(bufB, bufA, 7)
#undef PROD_CHUNK
    } else {
        // ======================= CONSUMERS =======================
        const int cw = w - 4;
        const int nbase = cw * 32;      // this wave's 32 n-rows
        const ushort* cb0 = Cbf + r * DD + q * 8;
        const ushort* cb1 = cb0 + 16 * DD;

        f32x4 aA0 = {0.f,0.f,0.f,0.f}, aA1 = {0.f,0.f,0.f,0.f};
        f32x4 aB0 = {0.f,0.f,0.f,0.f}, aB1 = {0.f,0.f,0.f,0.f};

        for (int c = 0; c < 8; ++c) {
            short8 cf0[2], cf1[2];
#pragma unroll
            for (int u = 0; u < 2; ++u) {
                cf0[u] = *reinterpret_cast<const short8*>(cb0 + (c * 2 + u) * 32);
                cf1[u] = *reinterpret_cast<const short8*>(cb1 + (c * 2 + u) * 32);
            }
            volatile int* vf = &flags[c][0];
            while (!(vf[0] & vf[1] & vf[2] & vf[3]))
                __builtin_amdgcn_s_sleep(1);
            asm volatile("" ::: "memory");          // no tile reads above this
            __builtin_amdgcn_sched_barrier(0);
#pragma unroll
            for (int u = 0; u < 2; ++u) {
                const int s = c * 2 + u;
                union { short8 s8; ushort us[8]; } af0, af1;
#pragma unroll
                for (int jj = 0; jj < 8; ++jj) {
                    const int dA = s * 32 + q * 8 + jj;
                    const int key = swzkey(dA);
                    af0.us[jj] = tile[dA * WIN + ((nbase + r) ^ key)];
                    af1.us[jj] = tile[dA * WIN + ((nbase + 16 + r) ^ key)];
                }
                aA0 = __builtin_amdgcn_mfma_f32_16x16x32_bf16(af0.s8, cf0[u], aA0, 0, 0, 0);
                aA1 = __builtin_amdgcn_mfma_f32_16x16x32_bf16(af0.s8, cf1[u], aA1, 0, 0, 0);
                aB0 = __builtin_amdgcn_mfma_f32_16x16x32_bf16(af1.s8, cf0[u], aB0, 0, 0, 0);
                aB1 = __builtin_amdgcn_mfma_f32_16x16x32_bf16(af1.s8, cf1[u], aB1, 0, 0, 0);
            }
        }

        // x2s for this wave's 32 n (producers all done: flags[7] observed)
        if (l < 32) {
            float s = 0.f;
#pragma unroll
            for (int j = 0; j < 8; ++j) s += x2part[j][nbase + l];
            x2s[nbase + l] = s;
        }

        // softmax for the two 16-n frags
        const float sk0 = scale[r], sk1 = scale[r + 16];
        const float sq0 = sc2[r],  sq1 = sc2[r + 16];
        float as0 = 0.f, as1 = 0.f;
#define SOFTMAX_FRAG(A0, A1, F)                                                \
        {                                                                      \
            float e0v[4], e1v[4];                                              \
            _Pragma("unroll")                                                  \
            for (int i = 0; i < 4; ++i) {                                      \
                const float x2v = x2s[nbase + (F) * 16 + 4 * q + i];           \
                float sl0 = fmaf(sk0, x2v, sq0) - 2.f * sk0 * A0[i];           \
                float sl1 = fmaf(sk1, x2v, sq1) - 2.f * sk1 * A1[i];           \
                float m = fmaxf(sl0, sl1);                                     \
                m = fmaxf(m, __shfl_xor(m, 1));                                \
                m = fmaxf(m, __shfl_xor(m, 2));                                \
                m = fmaxf(m, __shfl_xor(m, 4));                                \
                m = fmaxf(m, __shfl_xor(m, 8));                                \
                float e0 = __expf(sl0 - m), e1 = __expf(sl1 - m);              \
                float ssum = e0 + e1;                                          \
                ssum += __shfl_xor(ssum, 1);                                   \
                ssum += __shfl_xor(ssum, 2);                                   \
                ssum += __shfl_xor(ssum, 4);                                   \
                ssum += __shfl_xor(ssum, 8);                                   \
                const float inv = 1.f / ssum;                                  \
                e0 *= inv; e1 *= inv;                                          \
                if (n0 + nbase + (F) * 16 + 4 * q + i >= NN) { e0 = 0.f; e1 = 0.f; } \
                e0v[i] = e0; e1v[i] = e1;                                      \
                as0 += e0; as1 += e1;                                          \
            }                                                                  \
            const int ncol = nbase + (F) * 16 + 4 * q;                         \
            *reinterpret_cast<uint2*>(&As2[r * WIN + (ncol ^ swzkey(r))]) =    \
                make_uint2(bf16pack(e0v[0], e0v[1]), bf16pack(e0v[2], e0v[3]));\
            *reinterpret_cast<uint2*>(&As2[(r + 16) * WIN + (ncol ^ swzkey(r + 16))]) = \
                make_uint2(bf16pack(e1v[0], e1v[1]), bf16pack(e1v[2], e1v[3]));\
        }
        SOFTMAX_FRAG(aA0, aA1, 0)
        SOFTMAX_FRAG(aB0, aB1, 1)
#undef SOFTMAX_FRAG

        as0 += __shfl_xor(as0, 16); as0 += __shfl_xor(as0, 32);
        as1 += __shfl_xor(as1, 16); as1 += __shfl_xor(as1, 32);
        if (l < 16) { asw[cw][r] = as0; asw[cw][r + 16] = as1; }
    }

    __syncthreads();   // tile + As2 + asw complete; everything drained

    if (t < KK) {
        float s = 0.f;
#pragma unroll
        for (int j = 0; j < 4; ++j) s += asw[j][t];
        asum_part[((size_t)b * SB + sb) * KK + t] = s;
    }

    // ---- phase B: GEMM2; wave w owns d in [w*64, w*64+64) ----
    short8 bfr0[4], bfr1[4];
#pragma unroll
    for (int step = 0; step < 4; ++step) {
        bfr0[step] = *reinterpret_cast<const short8*>(
            &As2[r * WIN + ((step * 32 + q * 8) ^ swzkey(r))]);
        bfr1[step] = *reinterpret_cast<const short8*>(
            &As2[(r + 16) * WIN + ((step * 32 + q * 8) ^ swzkey(r + 16))]);
    }

    f32x4 acc[4][2];
#pragma unroll
    for (int df = 0; df < 4; ++df) {
        acc[df][0] = (f32x4){0.f, 0.f, 0.f, 0.f};
        acc[df][1] = (f32x4){0.f, 0.f, 0.f, 0.f};
    }

#pragma unroll
    for (int df = 0; df < 4; ++df) {
        const int d = w * 64 + df * 16 + r;   // A-frag row
        const int kd = swzkey(d);
#pragma unroll
        for (int step = 0; step < 4; ++step) {
            const short8 xa = *reinterpret_cast<const short8*>(
                &tile[d * WIN + ((step * 32 + q * 8) ^ kd)]);
            acc[df][0] = __builtin_amdgcn_mfma_f32_16x16x32_bf16(
                xa, bfr0[step], acc[df][0], 0, 0, 0);
            acc[df][1] = __builtin_amdgcn_mfma_f32_16x16x32_bf16(
                xa, bfr1[step], acc[df][1], 0, 0, 0);
        }
    }

    // ---- store Ep partial (fp32): D-frag rows q*4+i are d-contiguous ----
    float* ep = Ep + (size_t)(b * SB + sb) * KK * DD;
#pragma unroll
    for (int df = 0; df < 4; ++df) {
#pragma unroll
        for (int kf = 0; kf < 2; ++kf) {
            const int k = kf * 16 + r;
            const int d = w * 64 + df * 16 + q * 4;
            *reinterpret_cast<f32x4*>(ep + (size_t)k * DD + d) = acc[df][kf];
        }
    }
}

// ---------------------------------------------------------------------------
// K3: E[b,k,d] = sum_sb Ep[b,sb,k,d] - Asum[b,k]*C[k,d]
// Grid: B*K = 512 blocks x 256 threads (2 d's per thread).
// ---------------------------------------------------------------------------
__global__ __launch_bounds__(256) void k3_final(const float* __restrict__ Ep,
                                                const float* __restrict__ asum_part,
                                                const float* __restrict__ Cw,
                                                float* __restrict__ E) {
    const int t = threadIdx.x;
    const int b = blockIdx.x >> 5, k = blockIdx.x & 31;

    float asum = 0.f;
#pragma unroll
    for (int sb = 0; sb < SB; ++sb)
        asum += asum_part[((size_t)b * SB + sb) * KK + k];

#pragma unroll
    for (int h = 0; h < 2; ++h) {
        const int d = t + h * 256;
        float s2 = 0.f;
#pragma unroll 4
        for (int sb = 0; sb < SB; ++sb)
            s2 += Ep[(((size_t)b * SB + sb) * KK + k) * DD + d];
        E[((size_t)b * KK + k) * DD + d] = s2 - asum * Cw[k * DD + d];
    }
}

// ---------------------------------------------------------------------------
extern "C" void kernel_launch(void* const* d_in, const int* in_sizes, int n_in,
                              void* d_out, int out_size, void* d_ws, size_t ws_size,
                              hipStream_t stream) {
    const float* X     = (const float*)d_in[0];
    const float* Cw    = (const float*)d_in[1];
    const float* scale = (const float*)d_in[2];
    float* E = (float*)d_out;

    // ws layout (float slots):
    //   Ep        : 16*29*32*512 = 7,602,176
    //   asum_part : 464*32       = 14,848
    //   sc2       : 32
    //   Cbf       : 32*512 ushort = 8192 float slots        (~30.5 MB total)
    float* ws = (float*)d_ws;
    float* Ep = ws;
    float* asum_part = Ep + (size_t)BB * SB * KK * DD;
    float* sc2 = asum_part + (size_t)BB * SB * KK;
    ushort* Cbf = (ushort*)(sc2 + KK);

    k0_prep<<<dim3(1), dim3(256), 0, stream>>>(Cw, scale, Cbf, sc2);
    kf_fused<<<dim3(BB * SB), dim3(512), 0, stream>>>(X, Cbf, scale, sc2, Ep, asum_part);
    k3_final<<<dim3(BB * KK), dim3(256), 0, stream>>>(Ep, asum_part, Cw, E);
}